// Round 11
// baseline (1384.557 us; speedup 1.0000x reference)
//
#include <hip/hip_runtime.h>
#include <math.h>

#define NTHREADS 256
#define IN_C 128
#define HID 64
#define OUT_C 40
#define N_LAYERS 8
#define ALPHA 0.1f
#define BN_EPS 1e-5f

typedef float f32x4 __attribute__((ext_vector_type(4)));
typedef _Float16 f16;
typedef _Float16 f16x4 __attribute__((ext_vector_type(4)));
typedef _Float16 f16x8 __attribute__((ext_vector_type(8)));

// LDS tile row stride in f16 units: 72 (=144 B, 16B-aligned, 2-way bank alias)
#define TPAD 72

__device__ __forceinline__ f32x4 ld4(const float* p) { return *(const f32x4*)p; }

__device__ __forceinline__ f32x4 ldh4(const f16* p) {
  f16x4 v = *(const f16x4*)p;
  return __builtin_convertvector(v, f32x4);
}

__device__ __forceinline__ f32x4 bnrelu(f32x4 v, f32x4 k1, f32x4 k2) {
  f32x4 r = v * k1 + k2;
  r.x = fmaxf(r.x, 0.f); r.y = fmaxf(r.y, 0.f);
  r.z = fmaxf(r.z, 0.f); r.w = fmaxf(r.w, 0.f);
  return r;
}

__device__ __forceinline__ float bcast(float v, int lane) {
  return __int_as_float(__builtin_amdgcn_readlane(__float_as_int(v), lane));
}

// ---------------- setup kernels ----------------

// sums layout: per-layer slot l at [l*1024], channel c at offset c*16
__global__ void k_zero(int* __restrict__ cnt, float* __restrict__ sumP,
                       float* __restrict__ sumsqP, int* __restrict__ ewpad,
                       int n) {
  int i = blockIdx.x * NTHREADS + threadIdx.x;
  if (i < n) cnt[i] = 0;
  if (i < N_LAYERS * 1024) { sumP[i] = 0.f; sumsqP[i] = 0.f; }
  if (i < 16) ewpad[i] = 0;  // tail-safe pad records
}

__global__ void k_hist(const int* __restrict__ col, int* __restrict__ cnt, int E) {
  int e = blockIdx.x * NTHREADS + threadIdx.x;
  if (e < E) atomicAdd(&cnt[col[e]], 1);
}

// scan pass 1 + dinv (deg = cnt + self loop)
__global__ void k_scan1(const int* __restrict__ cnt, int* __restrict__ offs,
                        int* __restrict__ partials, float* __restrict__ dinv,
                        int n) {
  __shared__ int sh[NTHREADS];
  int t = threadIdx.x, i = blockIdx.x * NTHREADS + t;
  int v = (i < n) ? cnt[i] : 0;
  if (i < n) dinv[i] = rsqrtf((float)v + 1.0f);
  sh[t] = v;
  __syncthreads();
  int run = v;
  for (int d = 1; d < NTHREADS; d <<= 1) {
    int add = (t >= d) ? sh[t - d] : 0;
    __syncthreads();
    run += add;
    sh[t] = run;
    __syncthreads();
  }
  if (i < n) offs[i] = run - v;
  if (t == NTHREADS - 1) partials[blockIdx.x] = run;
}

__global__ void k_scan2(int* __restrict__ partials, int nb) {
  __shared__ int sh[512];
  int t = threadIdx.x;
  int v = (t < nb) ? partials[t] : 0;
  sh[t] = v;
  __syncthreads();
  int run = v;
  for (int d = 1; d < 512; d <<= 1) {
    int add = (t >= d) ? sh[t - d] : 0;
    __syncthreads();
    run += add;
    sh[t] = run;
    __syncthreads();
  }
  if (t < nb) partials[t] = run - v;
}

__global__ void k_scan3(int* __restrict__ offs, int* __restrict__ cur,
                        const int* __restrict__ partials, int n, int E) {
  int i = blockIdx.x * NTHREADS + threadIdx.x;
  if (i < n) {
    int v = offs[i] + partials[i >> 8];
    offs[i] = v;
    cur[i] = v;
  }
  if (i == 0) offs[n] = E;
}

// CSR fill, 4B src-only records (weight dinv[src] is folded into hp rows)
__global__ void k_fill(const int* __restrict__ row, const int* __restrict__ col,
                       int* __restrict__ cur, int* __restrict__ ew, int E) {
  int e = blockIdx.x * NTHREADS + threadIdx.x;
  if (e < E) {
    int cl = col[e];
    int rw = row[e];
    int pos = atomicAdd(&cur[cl], 1);
    ew[pos] = rw;
  }
}

// ---------------- h0 = relu(x@W0+b0) (fp16) and hp = dinv*h0 ----------------
__global__ __launch_bounds__(NTHREADS) void k_gemm0(
    const float* __restrict__ x, const float* __restrict__ W0,
    const float* __restrict__ b0, const float* __restrict__ dinv,
    f16* __restrict__ h016, f16* __restrict__ hp, int n) {
  int t = threadIdx.x;
  int lane = t & 63;
  int c = lane;
  float Wc[IN_C];
#pragma unroll
  for (int k = 0; k < IN_C; k++) Wc[k] = W0[k * HID + c];
  float bias = b0[c];
  int half = lane >> 5, li = lane & 31;
  int wg = blockIdx.x * (NTHREADS / 64) + (t >> 6);
  int NW = gridDim.x * (NTHREADS / 64);
  int npairs = (n + 1) >> 1;
  for (int p = wg; p < npairs; p += NW) {
    int r = 2 * p + half;
    f32x4 xv = {0.f, 0.f, 0.f, 0.f};
    if (r < n) xv = ld4(x + (size_t)r * IN_C + li * 4);
    float acc0 = bias, acc1 = bias;
#pragma unroll
    for (int k = 0; k < IN_C; k++) {
      int sl = k >> 2;
      float comp = xv[k & 3];
      float a0 = bcast(comp, sl);
      float a1 = bcast(comp, 32 + sl);
      acc0 += a0 * Wc[k];
      acc1 += a1 * Wc[k];
    }
    acc0 = fmaxf(acc0, 0.f);
    acc1 = fmaxf(acc1, 0.f);
    int r0 = 2 * p, r1 = 2 * p + 1;
    if (r0 < n) {
      float d0 = dinv[r0];
      h016[(size_t)r0 * HID + c] = (f16)acc0;
      hp[(size_t)r0 * HID + c] = (f16)(d0 * acc0);
    }
    if (r1 < n) {
      float d1 = dinv[r1];
      h016[(size_t)r1 * HID + c] = (f16)acc1;
      hp[(size_t)r1 * HID + c] = (f16)(d1 * acc1);
    }
  }
}

// ---------------- fused gather + MFMA conv + BN stats ----------------
// Per 16-row tile: 4 waves gather 4 rows each (one row per 16-lane group,
// 8-deep edge chunks) -> sval rows staged in a 16x72-f16 LDS tile -> each
// wave computes its 16-col tile of S2 = SV @ W' with 2 x mfma_f32_16x16x32_f16
// (W' = (1-beta)I + beta*W folded into the B-frag at kernel start).
// Grid-strided (1563 blocks x ~4 tiles) so stats atomics stay at r10's count.
// No launch_bounds (r4/5/7: tight VGPR caps spill loop state to scratch).
__global__ void k_gconv(
    const f16* __restrict__ hp, const f16* __restrict__ h0,
    const float* __restrict__ dinv, const int* __restrict__ offs,
    const int* __restrict__ ew, const float* __restrict__ Wl,
    f16* __restrict__ sout, float* __restrict__ sumL,
    float* __restrict__ sumsqL, float beta, int n) {
  __shared__ f16 st[16 * TPAD];  // 2.25 KB tile
  int t = threadIdx.x;
  int lane = t & 63, wid = t >> 6;
  int eg = lane >> 4, li = lane & 15, c4 = li << 2;
  int lm = lane & 15, lk = lane >> 4;
  // B-frag for this wave's col-tile: col = wid*16+lm, k = ks*32 + lk*8 + i
  f16x8 bf[2];
  {
    int c = wid * 16 + lm;
#pragma unroll
    for (int ks = 0; ks < 2; ks++) {
#pragma unroll
      for (int i = 0; i < 8; i++) {
        int k = ks * 32 + lk * 8 + i;
        float wv = beta * Wl[k * HID + c];
        if (k == c) wv += (1.f - beta);
        bf[ks][i] = (f16)wv;
      }
    }
  }
  float ssum = 0.f, ssq = 0.f;
  int nblk = (n + 15) >> 4;
  for (int blk = blockIdx.x; blk < nblk; blk += gridDim.x) {
    int r0 = blk * 16;
    // ---- gather phase: this group's row ----
    int i = r0 + wid * 4 + eg;
    f32x4 sval = {0.f, 0.f, 0.f, 0.f};
    if (i < n) {
      int jb = offs[i], je = offs[i + 1];
      float di = dinv[i];
      f16x4 hs16 = *(const f16x4*)(hp + (size_t)i * HID + c4);
      f16x4 h016v = *(const f16x4*)(h0 + (size_t)i * HID + c4);
      f32x4 acc = {0.f, 0.f, 0.f, 0.f};
      int j = jb;
      for (; j + 8 <= je; j += 8) {
        int q0 = ew[j + 0];
        int q1 = ew[j + 1];
        int q2 = ew[j + 2];
        int q3 = ew[j + 3];
        int q4 = ew[j + 4];
        int q5 = ew[j + 5];
        int q6 = ew[j + 6];
        int q7 = ew[j + 7];
        f16x4 u0 = *(const f16x4*)(hp + (size_t)q0 * HID + c4);
        f16x4 u1 = *(const f16x4*)(hp + (size_t)q1 * HID + c4);
        f16x4 u2 = *(const f16x4*)(hp + (size_t)q2 * HID + c4);
        f16x4 u3 = *(const f16x4*)(hp + (size_t)q3 * HID + c4);
        f16x4 u4 = *(const f16x4*)(hp + (size_t)q4 * HID + c4);
        f16x4 u5 = *(const f16x4*)(hp + (size_t)q5 * HID + c4);
        f16x4 u6 = *(const f16x4*)(hp + (size_t)q6 * HID + c4);
        f16x4 u7 = *(const f16x4*)(hp + (size_t)q7 * HID + c4);
        acc += __builtin_convertvector(u0, f32x4);
        acc += __builtin_convertvector(u1, f32x4);
        acc += __builtin_convertvector(u2, f32x4);
        acc += __builtin_convertvector(u3, f32x4);
        acc += __builtin_convertvector(u4, f32x4);
        acc += __builtin_convertvector(u5, f32x4);
        acc += __builtin_convertvector(u6, f32x4);
        acc += __builtin_convertvector(u7, f32x4);
      }
      for (; j < je; j++) {
        acc += ldh4(hp + (size_t)ew[j] * HID + c4);
      }
      f32x4 hs = __builtin_convertvector(hs16, f32x4);
      f32x4 h0v = __builtin_convertvector(h016v, f32x4);
      sval = (1.f - ALPHA) * (di * (acc + hs)) + ALPHA * h0v;
    }
    // stage row into LDS (inactive rows stage zeros)
    int rl = wid * 4 + eg;
    *(f16x4*)(st + rl * TPAD + c4) = __builtin_convertvector(sval, f16x4);
    __syncthreads();
    // ---- MFMA phase: this wave's 16-col tile over all 16 rows ----
    const f16* ap = st + lm * TPAD + lk * 8;
    f16x8 a0 = *(const f16x8*)(ap);
    f16x8 a1 = *(const f16x8*)(ap + 32);
    f32x4 z = {0.f, 0.f, 0.f, 0.f};
    z = __builtin_amdgcn_mfma_f32_16x16x32_f16(a0, bf[0], z, 0, 0, 0);
    z = __builtin_amdgcn_mfma_f32_16x16x32_f16(a1, bf[1], z, 0, 0, 0);
#pragma unroll
    for (int reg = 0; reg < 4; reg++) {
      int r = r0 + lk * 4 + reg;
      if (r < n) {
        float v = z[reg];
        sout[(size_t)r * HID + wid * 16 + lm] = (f16)v;
        ssum += v;
        ssq += v * v;
      }
    }
    __syncthreads();  // WAR: LDS reused next tile
  }
  // stats: lanes lm, lm+16, lm+32, lm+48 share channel wid*16+lm
  ssum += __shfl_xor(ssum, 16); ssum += __shfl_xor(ssum, 32);
  ssq += __shfl_xor(ssq, 16);  ssq += __shfl_xor(ssq, 32);
  if (lk == 0) {
    atomicAdd(&sumL[(wid * 16 + lm) * 16], ssum);
    atomicAdd(&sumsqL[(wid * 16 + lm) * 16], ssq);
  }
}

// per-block inline BN-affine from the sums slot
__device__ __forceinline__ void stats_to_lds(
    const float* __restrict__ sumL, const float* __restrict__ sumsqL,
    const float* __restrict__ gamma_l, const float* __restrict__ beta_l,
    float* ms, int t, int n) {
  if (t < 64) {
    float s = sumL[t * 16], sq = sumsqL[t * 16];
    float mu = s / (float)n;
    float var = sq / (float)n - mu * mu;
    float iv = rsqrtf(var + BN_EPS);
    float k1 = iv * gamma_l[t];
    ms[t] = k1;
    ms[64 + t] = beta_l[t] - mu * k1;
  }
  __syncthreads();
}

// hp = dinv * relu(BN(s)): the pre-scaled gather operand for the next layer
__global__ __launch_bounds__(NTHREADS) void k_bnrelu(
    const f16* __restrict__ s, const float* __restrict__ sumL,
    const float* __restrict__ sumsqL, const float* __restrict__ gamma_l,
    const float* __restrict__ beta_l, const float* __restrict__ dinv,
    f16* __restrict__ hp, int n) {
  __shared__ __align__(16) float ms[128];
  int t = threadIdx.x;
  stats_to_lds(sumL, sumsqL, gamma_l, beta_l, ms, t, n);
  int idx = blockIdx.x * NTHREADS + t;  // x4 index
  if (idx < n * (HID / 4)) {
    int c4 = idx & 15;
    int row = idx >> 4;
    f32x4 v = ldh4(s + (size_t)idx * 4);
    f32x4 k1 = *(const f32x4*)(ms + c4 * 4);
    f32x4 k2 = *(const f32x4*)(ms + 64 + c4 * 4);
    v = bnrelu(v, k1, k2);
    float di = dinv[row];
    v = di * v;
    ((f16x4*)hp)[idx] = __builtin_convertvector(v, f16x4);
  }
}

// out = relu(BN_7(s)) @ W_out + b_out   (affine computed inline from slot 7)
__global__ __launch_bounds__(NTHREADS) void k_out(
    const f16* __restrict__ s, const float* __restrict__ sumL,
    const float* __restrict__ sumsqL, const float* __restrict__ gamma_l,
    const float* __restrict__ beta_l, const float* __restrict__ Wout,
    const float* __restrict__ bout, float* __restrict__ out, int n) {
  __shared__ float Ws[HID * OUT_C];
  __shared__ float bs[OUT_C];
  __shared__ __align__(16) float ms[128];
  int t = threadIdx.x;
  for (int m = t; m < HID * OUT_C; m += NTHREADS) Ws[m] = Wout[m];
  if (t < OUT_C) bs[t] = bout[t];
  stats_to_lds(sumL, sumsqL, gamma_l, beta_l, ms, t, n);
  int idx = blockIdx.x * NTHREADS + t;
  if (idx < n * OUT_C) {
    int row = idx / OUT_C;
    int c = idx - row * OUT_C;
    float acc = bs[c];
    const f16* sr = s + (size_t)row * HID;
    for (int kk = 0; kk < HID / 4; kk++) {
      f32x4 a = ldh4(sr + kk * 4);
      f32x4 k1 = *(const f32x4*)(ms + kk * 4);
      f32x4 k2 = *(const f32x4*)(ms + 64 + kk * 4);
      a = bnrelu(a, k1, k2);
      int k = kk * 4;
      acc += a.x * Ws[(k + 0) * OUT_C + c] + a.y * Ws[(k + 1) * OUT_C + c] +
             a.z * Ws[(k + 2) * OUT_C + c] + a.w * Ws[(k + 3) * OUT_C + c];
    }
    out[idx] = acc;
  }
}

// ---------------- host ----------------

extern "C" void kernel_launch(void* const* d_in, const int* in_sizes, int n_in,
                              void* d_out, int out_size, void* d_ws, size_t ws_size,
                              hipStream_t stream) {
  const float* x = (const float*)d_in[0];
  const int* ei = (const int*)d_in[1];
  const float* W0 = (const float*)d_in[2];
  const float* b0 = (const float*)d_in[3];
  const float* convW = (const float*)d_in[4];
  const float* bn_gamma = (const float*)d_in[5];
  const float* bn_beta = (const float*)d_in[6];
  const float* W_out = (const float*)d_in[7];
  const float* b_out = (const float*)d_in[8];
  float* out = (float*)d_out;

  int n = in_sizes[0] / IN_C;   // 100000
  int E = in_sizes[1] / 2;      // 1600000
  const int* row = ei;
  const int* col = ei + E;

  char* w = (char*)d_ws;
  auto alloc = [&](size_t bytes) {
    char* p = w;
    w += (bytes + 255) & ~(size_t)255;
    return p;
  };
  float* dinv    = (float*)alloc((size_t)n * 4);
  int*   cnt     = (int*)alloc((size_t)n * 4);
  int*   offs    = (int*)alloc((size_t)(n + 1) * 4);
  int*   cur     = (int*)alloc((size_t)n * 4);
  int*   partials= (int*)alloc(512 * 4);
  int*   ew      = (int*)alloc((size_t)(E + 16) * 4);   // 4B records + pad
  f16*   h016    = (f16*)alloc((size_t)n * HID * 2);
  f16*   hp      = (f16*)alloc((size_t)n * HID * 2);    // dinv * relu(BN(s))
  f16*   sb      = (f16*)alloc((size_t)n * HID * 2);    // layer output s_l
  float* sumP    = (float*)alloc((size_t)N_LAYERS * 1024 * 4);
  float* sumsqP  = (float*)alloc((size_t)N_LAYERS * 1024 * 4);

  int gN = (n + NTHREADS - 1) / NTHREADS;   // 391
  int gE = (E + NTHREADS - 1) / NTHREADS;   // 6250
  int gRow = (n + 15) / 16;                 // 6250 tiles
  int gConv = (gRow + 3) / 4;               // 1563 blocks, ~4 tiles each
  int gV = (n * (HID / 4) + NTHREADS - 1) / NTHREADS;

  k_zero<<<gN, NTHREADS, 0, stream>>>(cnt, sumP, sumsqP, ew + E, n);
  k_hist<<<gE, NTHREADS, 0, stream>>>(col, cnt, E);
  k_scan1<<<gN, NTHREADS, 0, stream>>>(cnt, offs, partials, dinv, n);
  k_scan2<<<1, 512, 0, stream>>>(partials, gN);
  k_scan3<<<gN, NTHREADS, 0, stream>>>(offs, cur, partials, n, E);
  k_fill<<<gE, NTHREADS, 0, stream>>>(row, col, cur, ew, E);

  k_gemm0<<<1024, NTHREADS, 0, stream>>>(x, W0, b0, dinv, h016, hp, n);

  for (int l = 0; l < N_LAYERS; l++) {
    float beta = logf(0.5f / (float)(l + 1) + 1.0f);
    if (l > 0) {  // hp = dinv * relu(BN_{l-1}(s_{l-1})) using slot l-1
      k_bnrelu<<<gV, NTHREADS, 0, stream>>>(
          sb, sumP + (size_t)(l - 1) * 1024, sumsqP + (size_t)(l - 1) * 1024,
          bn_gamma + (l - 1) * HID, bn_beta + (l - 1) * HID, dinv, hp, n);
    }
    k_gconv<<<gConv, NTHREADS, 0, stream>>>(
        hp, h016, dinv, offs, ew, convW + (size_t)l * HID * HID, sb,
        sumP + (size_t)l * 1024, sumsqP + (size_t)l * 1024, beta, n);
  }

  // s_7 in sb; k_out applies BN_7 (slot 7) + relu inline, then output GEMM
  k_out<<<((size_t)n * OUT_C + NTHREADS - 1) / NTHREADS, NTHREADS, 0, stream>>>(
      sb, sumP + (size_t)7 * 1024, sumsqP + (size_t)7 * 1024,
      bn_gamma + 7 * HID, bn_beta + 7 * HID, W_out, b_out, out, n);
}